// Round 1
// baseline (259.984 us; speedup 1.0000x reference)
//
#include <hip/hip_runtime.h>
#include <math.h>

// FlexibleLogisticModel: out = sigmoid( sum_f w[f] * alphas[ord(f)] * phi_f(x) )
// where phi_f enumerates all monomials of degree 0..4 over D=64 variables in
// combinations_with_replacement (lexicographic) order. We exploit the known
// enumeration order to decode feature index -> (i<=j<=k<=l) analytically,
// never touching the 208 MB exponent matrix E.

#define DVARS 64
#define F_TOTAL 814385u
// feature-range offsets per order
#define OFF1 1u        // order-1 starts here (64 features)
#define OFF2 65u       // order-2 starts here (2080 features)
#define OFF3 2145u     // order-3 starts here (45760 features)
#define OFF4 47905u    // order-4 starts here (766480 features)

#define BLOCK 256
#define NBLOCKS ((F_TOTAL + BLOCK - 1) / BLOCK)   // 3182

// find largest i in [lo, 63] with arr[i] <= target  (arr strictly increasing)
__device__ __forceinline__ unsigned ub_search(const unsigned* __restrict__ arr,
                                              unsigned target, unsigned lo) {
    unsigned hi = 63u;
    while (lo < hi) {
        unsigned mid = (lo + hi + 1u) >> 1;
        if (arr[mid] <= target) lo = mid; else hi = mid - 1u;
    }
    return lo;
}

__global__ __launch_bounds__(BLOCK)
void poly_partial_kernel(const float* __restrict__ x,
                         const float* __restrict__ w,
                         const float* __restrict__ alphas,
                         float* __restrict__ partial) {
    __shared__ float xs[DVARS];
    __shared__ float as[5];
    // cumulative combo-count tables (hockey-stick sums):
    // G2[a] = sum_{b<a} C(64-b,1)   (total 2080 at a=64)
    // G3[a] = sum_{b<a} C(65-b,2)   (total 45760)
    // B4[a] = sum_{b<a} C(66-b,3)   (total 766480)
    __shared__ unsigned G2[65], G3[65], B4[65];
    __shared__ float wsum[BLOCK / 64];

    const int tid = threadIdx.x;
    if (tid < DVARS) xs[tid] = x[tid];
    if (tid < 5)     as[tid] = alphas[tid];
    if (tid < 65) {
        unsigned a = (unsigned)tid;
        G2[a] = a * 64u - (a * (a - 1u)) / 2u;
        unsigned g3 = 0u, b4 = 0u;
        for (unsigned b = 0u; b < a; ++b) {
            unsigned n = 64u - b;
            g3 += n * (n + 1u) / 2u;
            b4 += n * (n + 1u) * (n + 2u) / 6u;
        }
        G3[a] = g3;
        B4[a] = b4;
    }
    __syncthreads();

    const unsigned f = blockIdx.x * (unsigned)BLOCK + (unsigned)tid;
    float val = 0.0f;
    if (f < F_TOTAL) {
        float phi, alpha;
        if (f == 0u) {                       // order 0
            phi = 1.0f; alpha = as[0];
        } else if (f < OFF2) {               // order 1
            phi = xs[f - OFF1]; alpha = as[1];
        } else if (f < OFF3) {               // order 2: (i<=j)
            unsigned r = f - OFF2;
            unsigned i = ub_search(G2, r, 0u);
            unsigned j = i + (r - G2[i]);
            phi = xs[i] * xs[j]; alpha = as[2];
        } else if (f < OFF4) {               // order 3: (i<=j<=k)
            unsigned r = f - OFF3;
            unsigned i = ub_search(G3, r, 0u);
            unsigned r2 = r - G3[i];
            unsigned j = ub_search(G2, r2 + G2[i], i);
            unsigned r3 = r2 - (G2[j] - G2[i]);
            unsigned k = j + r3;
            phi = xs[i] * xs[j] * xs[k]; alpha = as[3];
        } else {                             // order 4: (i<=j<=k<=l)
            unsigned r = f - OFF4;
            unsigned i = ub_search(B4, r, 0u);
            unsigned r2 = r - B4[i];
            unsigned j = ub_search(G3, r2 + G3[i], i);
            unsigned r3 = r2 - (G3[j] - G3[i]);
            unsigned k = ub_search(G2, r3 + G2[j], j);
            unsigned r4 = r3 - (G2[k] - G2[j]);
            unsigned l = k + r4;
            phi = xs[i] * xs[j] * xs[k] * xs[l]; alpha = as[4];
        }
        val = alpha * phi * w[f];
    }

    // wave (64-lane) tree reduce
    #pragma unroll
    for (int off = 32; off > 0; off >>= 1)
        val += __shfl_down(val, off);
    const int wave = tid >> 6;
    if ((tid & 63) == 0) wsum[wave] = val;
    __syncthreads();
    if (tid == 0) {
        float s = 0.0f;
        #pragma unroll
        for (int v = 0; v < BLOCK / 64; ++v) s += wsum[v];
        partial[blockIdx.x] = s;
    }
}

__global__ __launch_bounds__(BLOCK)
void reduce_sigmoid_kernel(const float* __restrict__ partial, int n,
                           float* __restrict__ out) {
    __shared__ float wsum[BLOCK / 64];
    const int tid = threadIdx.x;
    float s = 0.0f;
    for (int idx = tid; idx < n; idx += BLOCK) s += partial[idx];
    #pragma unroll
    for (int off = 32; off > 0; off >>= 1)
        s += __shfl_down(s, off);
    if ((tid & 63) == 0) wsum[tid >> 6] = s;
    __syncthreads();
    if (tid == 0) {
        float fsum = 0.0f;
        #pragma unroll
        for (int v = 0; v < BLOCK / 64; ++v) fsum += wsum[v];
        out[0] = 1.0f / (1.0f + expf(-fsum));
    }
}

extern "C" void kernel_launch(void* const* d_in, const int* in_sizes, int n_in,
                              void* d_out, int out_size, void* d_ws, size_t ws_size,
                              hipStream_t stream) {
    const float* x      = (const float*)d_in[0];   // [64]
    const float* w      = (const float*)d_in[1];   // [814385]
    const float* alphas = (const float*)d_in[2];   // [5]
    // d_in[3] (E) and d_in[4] (ord_ids) are compile-time-known constants; unused.
    float* out = (float*)d_out;
    float* partial = (float*)d_ws;                 // NBLOCKS floats

    poly_partial_kernel<<<dim3(NBLOCKS), dim3(BLOCK), 0, stream>>>(x, w, alphas, partial);
    reduce_sigmoid_kernel<<<dim3(1), dim3(BLOCK), 0, stream>>>(partial, (int)NBLOCKS, out);
}

// Round 2
// 247.885 us; speedup vs baseline: 1.0488x; 1.0488x over previous
//
#include <hip/hip_runtime.h>
#include <math.h>

// FlexibleLogisticModel: out = sigmoid( sum_f w[f] * alphas[ord(f)] * phi_f(x) )
// phi_f enumerates all monomials of degree 0..4 over D=64 variables in
// combinations_with_replacement (lexicographic) order. We decode feature
// index -> (i<=j<=k<=l) analytically (never touching the 208 MB E matrix),
// and amortize the decode: order-4 features are handled 8-per-thread with
// one decode + 7 cheap lexicographic increments.

#define DVARS 64
#define F_TOTAL 814385u
#define OFF1 1u        // order-1 starts (64 features)
#define OFF2 65u       // order-2 starts (2080 features)
#define OFF3 2145u     // order-3 starts (45760 features)
#define OFF4 47905u    // order-4 starts (766480 features)

#define BLOCK 256
#define NSINGLE OFF4                     // 47905 one-feature threads (orders 0..3)
#define NMULTI ((F_TOTAL - OFF4) / 8u)   // 95810 eight-feature threads (order 4)
#define TOT_THREADS (NSINGLE + NMULTI)   // 143715
#define NBLOCKS ((TOT_THREADS + BLOCK - 1) / BLOCK)  // 562

// largest i in [lo, 63] with arr[i] <= target (arr strictly increasing)
__device__ __forceinline__ unsigned ub_search(const unsigned* __restrict__ arr,
                                              unsigned target, unsigned lo) {
    unsigned hi = 63u;
    while (lo < hi) {
        unsigned mid = (lo + hi + 1u) >> 1;
        if (arr[mid] <= target) lo = mid; else hi = mid - 1u;
    }
    return lo;
}

__global__ __launch_bounds__(BLOCK)
void poly_partial_kernel(const float* __restrict__ x,
                         const float* __restrict__ w,
                         const float* __restrict__ alphas,
                         float* __restrict__ partial) {
    __shared__ float xs[DVARS];
    __shared__ float as[5];
    // hockey-stick cumulative tables:
    // G2[a] = sum_{b<a} C(64-b,1); G3[a] = sum_{b<a} C(65-b,2); B4[a] = sum_{b<a} C(66-b,3)
    __shared__ unsigned G2[65], G3[65], B4[65];
    __shared__ float wsum[BLOCK / 64];

    const int tid = threadIdx.x;
    if (tid < DVARS) xs[tid] = x[tid];
    if (tid < 5)     as[tid] = alphas[tid];
    if (tid < 65) {
        unsigned a = (unsigned)tid;
        G2[a] = a * 64u - (a * (a - 1u)) / 2u;
        unsigned g3 = 0u, b4 = 0u;
        for (unsigned b = 0u; b < a; ++b) {
            unsigned n = 64u - b;
            g3 += n * (n + 1u) / 2u;
            b4 += n * (n + 1u) * (n + 2u) / 6u;
        }
        G3[a] = g3;
        B4[a] = b4;
    }
    __syncthreads();

    const unsigned gt = blockIdx.x * (unsigned)BLOCK + (unsigned)tid;
    float val = 0.0f;
    if (gt < NSINGLE) {                      // one feature, order 0..3
        const unsigned f = gt;
        float phi, alpha;
        if (f == 0u) {
            phi = 1.0f; alpha = as[0];
        } else if (f < OFF2) {
            phi = xs[f - OFF1]; alpha = as[1];
        } else if (f < OFF3) {               // (i<=j)
            unsigned r = f - OFF2;
            unsigned i = ub_search(G2, r, 0u);
            unsigned j = i + (r - G2[i]);
            phi = xs[i] * xs[j]; alpha = as[2];
        } else {                             // (i<=j<=k)
            unsigned r = f - OFF3;
            unsigned i = ub_search(G3, r, 0u);
            unsigned r2 = r - G3[i];
            unsigned j = ub_search(G2, r2 + G2[i], i);
            unsigned r3 = r2 - (G2[j] - G2[i]);
            unsigned k = j + r3;
            phi = xs[i] * xs[j] * xs[k]; alpha = as[3];
        }
        val = alpha * phi * w[f];
    } else if (gt < TOT_THREADS) {           // 8 consecutive order-4 features
        const unsigned t  = gt - NSINGLE;
        const unsigned f0 = OFF4 + 8u * t;
        unsigned r = 8u * t;
        unsigned i = ub_search(B4, r, 0u);
        unsigned r2 = r - B4[i];
        unsigned j = ub_search(G3, r2 + G3[i], i);
        unsigned r3 = r2 - (G3[j] - G3[i]);
        unsigned k = ub_search(G2, r3 + G2[j], j);
        unsigned l = k + (r3 - (G2[k] - G2[j]));

        float wv[8];
        #pragma unroll
        for (int q = 0; q < 8; ++q) wv[q] = w[f0 + (unsigned)q];

        float s = 0.0f;
        #pragma unroll
        for (int q = 0; q < 8; ++q) {
            s += wv[q] * (xs[i] * xs[j] * xs[k] * xs[l]);
            // lexicographic successor of (i<=j<=k<=l) in CWR order
            if (l < 63u)      { ++l; }
            else if (k < 63u) { ++k; l = k; }
            else if (j < 63u) { ++j; k = j; l = j; }
            else              { ++i; j = i; k = i; l = i; }
        }
        val = as[4] * s;
    }

    #pragma unroll
    for (int off = 32; off > 0; off >>= 1)
        val += __shfl_down(val, off);
    if ((tid & 63) == 0) wsum[tid >> 6] = val;
    __syncthreads();
    if (tid == 0) {
        float sb = 0.0f;
        #pragma unroll
        for (int v = 0; v < BLOCK / 64; ++v) sb += wsum[v];
        partial[blockIdx.x] = sb;
    }
}

__global__ __launch_bounds__(BLOCK)
void reduce_sigmoid_kernel(const float* __restrict__ partial, int n,
                           float* __restrict__ out) {
    __shared__ float wsum[BLOCK / 64];
    const int tid = threadIdx.x;
    float s = 0.0f;
    for (int idx = tid; idx < n; idx += BLOCK) s += partial[idx];
    #pragma unroll
    for (int off = 32; off > 0; off >>= 1)
        s += __shfl_down(s, off);
    if ((tid & 63) == 0) wsum[tid >> 6] = s;
    __syncthreads();
    if (tid == 0) {
        float fsum = 0.0f;
        #pragma unroll
        for (int v = 0; v < BLOCK / 64; ++v) fsum += wsum[v];
        out[0] = 1.0f / (1.0f + expf(-fsum));
    }
}

extern "C" void kernel_launch(void* const* d_in, const int* in_sizes, int n_in,
                              void* d_out, int out_size, void* d_ws, size_t ws_size,
                              hipStream_t stream) {
    const float* x      = (const float*)d_in[0];   // [64]
    const float* w      = (const float*)d_in[1];   // [814385]
    const float* alphas = (const float*)d_in[2];   // [5]
    // d_in[3] (E) and d_in[4] (ord_ids) are compile-time constants; unused.
    float* out = (float*)d_out;
    float* partial = (float*)d_ws;                 // NBLOCKS floats

    poly_partial_kernel<<<dim3(NBLOCKS), dim3(BLOCK), 0, stream>>>(x, w, alphas, partial);
    reduce_sigmoid_kernel<<<dim3(1), dim3(BLOCK), 0, stream>>>(partial, (int)NBLOCKS, out);
}